// Round 13
// baseline (100.860 us; speedup 1.0000x reference)
//
#include <hip/hip_runtime.h>
#include <math.h>

#define NQ 12
#define DIM 4096
#define NLAYER 4
#define NT 512

typedef float v2 __attribute__((ext_vector_type(2)));

__device__ __forceinline__ v2 mkv2(float a, float b) { v2 r; r.x = a; r.y = b; return r; }
__device__ __forceinline__ v2 sp(float a) { v2 r; r.x = a; r.y = a; return r; }
__device__ __forceinline__ v2 pkfma(v2 a, float b, v2 c) {
  return __builtin_elementwise_fma(a, sp(b), c);
}

// CNOT-cascade gather map (verified R1-R12): post-perm label y sits at sfun(y).
__device__ __forceinline__ int sfun(int z) {
  z ^= z >> 1; z ^= z >> 2; z ^= z >> 4; z ^= z >> 8; return z & (DIM - 1);
}
// Swizzle sigma2 (HW-validated R6/R7): XOR upper6 into low6, then bits3-5
// into bits0-2. All five access patterns conflict-free(<=2-way) under it.
__device__ __forceinline__ int swz(int s) {
  int m = s ^ ((s >> 6) & 63);
  return m ^ ((m >> 3) & 7);
}

__device__ __forceinline__ float4 block_reduce_sum4(float4 v, float4* red) {
  const int tid = threadIdx.x;
#pragma unroll
  for (int off = 32; off > 0; off >>= 1) {
    v.x += __shfl_down(v.x, off, 64);
    v.y += __shfl_down(v.y, off, 64);
    v.z += __shfl_down(v.z, off, 64);
    v.w += __shfl_down(v.w, off, 64);
  }
  if ((tid & 63) == 0) red[tid >> 6] = v;
  __syncthreads();
  if (tid == 0) {
    float4 s = make_float4(0.f, 0.f, 0.f, 0.f);
#pragma unroll
    for (int i = 0; i < NT / 64; ++i) {
      s.x += red[i].x; s.y += red[i].y; s.z += red[i].z; s.w += red[i].w;
    }
    red[0] = s;
  }
  __syncthreads();
  float4 r = red[0];
  __syncthreads();
  return r;
}

// Packed complex pair update, two rows at once (v_pk_fma_f32 material).
__device__ __forceinline__ void apply_pair(v2& r0, v2& i0, v2& r1, v2& i1,
    const float2 u00, const float2 u01, const float2 u10, const float2 u11) {
  v2 nr0 = pkfma(i1, -u01.y, pkfma(r1, u01.x, pkfma(i0, -u00.y, r0 * sp(u00.x))));
  v2 ni0 = pkfma(r1,  u01.y, pkfma(i1, u01.x, pkfma(r0,  u00.y, i0 * sp(u00.x))));
  v2 nr1 = pkfma(i1, -u11.y, pkfma(r1, u11.x, pkfma(i0, -u10.y, r0 * sp(u10.x))));
  v2 ni1 = pkfma(r1,  u11.y, pkfma(i1, u11.x, pkfma(r0,  u10.y, i0 * sp(u10.x))));
  r0 = nr0; i0 = ni0; r1 = nr1; i1 = ni1;
}

// Pass RT: reg slot-bit i holds z-bit (9-3*RT)+i -> qubit (2+3*RT)-i. (R7)
template <int RT>
__device__ __forceinline__ void gates3(v2 re[8], v2 im[8], const float2* GL) {
#pragma unroll
  for (int i = 0; i < 3; ++i) {
    const int q = 2 + 3 * RT - i;
    const float2 u00 = GL[q * 4 + 0], u01 = GL[q * 4 + 1];
    const float2 u10 = GL[q * 4 + 2], u11 = GL[q * 4 + 3];
#pragma unroll
    for (int pe = 0; pe < 4; ++pe) {
      const int e0 = ((pe >> i) << (i + 1)) | (pe & ((1 << i) - 1));
      const int e1 = e0 | (1 << i);
      apply_pair(re[e0], im[e0], re[e1], im[e1], u00, u01, u10, u11);
    }
  }
}

#define LOAD8(BUF, RE, IM, ADDR)            \
  _Pragma("unroll")                         \
  for (int j = 0; j < 8; ++j) {             \
    const float4 v = BUF[ADDR[j]];          \
    RE[j] = mkv2(v.x, v.y);                 \
    IM[j] = mkv2(v.z, v.w);                 \
  }
#define STORE8(BUF, RE, IM, ADDR)           \
  _Pragma("unroll")                         \
  for (int j = 0; j < 8; ++j)               \
    BUF[ADDR[j]] = make_float4(RE[j].x, RE[j].y, IM[j].x, IM[j].y);

__global__ __launch_bounds__(NT, 1) void qsim_kernel(
    const float* __restrict__ x, const float* __restrict__ w,
    float* __restrict__ out) {
  extern __shared__ __align__(16) char smem[];
  float4* stX  = (float4*)smem;                  // 64 KB: rows r0,r0+1
  float4* stY  = stX + DIM;                      // 64 KB: rows r0+2,r0+3
  float2* gmat = (float2*)(stY + DIM);           // 1.5 KB
  float4* red  = (float4*)(gmat + NLAYER * NQ * 4);  // 128 B

  const int t = threadIdx.x;
  const int lane = t & 63, wave = t >> 6;
  const int a = t & 7, b = (t >> 3) & 7;
  const long r0 = 4L * blockIdx.x;

  // --- gate matrices (48 gates, one thread each) ---
  if (t < NLAYER * NQ) {
    const float* wp = w + t * 3;
    float phi = wp[0], th = wp[1], om = wp[2];
    float sn, cc, sa, ca, sb, cb;
    sincosf(0.5f * th, &sn, &cc);
    sincosf(0.5f * (phi + om), &sa, &ca);
    sincosf(0.5f * (phi - om), &sb, &cb);
    float2* g = &gmat[t * 4];
    g[0] = make_float2(ca * cc, -sa * cc);   // U00
    g[1] = make_float2(-cb * sn, -sb * sn);  // U01
    g[2] = make_float2(cb * sn, -sb * sn);   // U10
    g[3] = make_float2(ca * cc, sa * cc);    // U11
  }

  // --- load 8 consecutive x from each of 4 rows, norms, encode ---
  const float4* xA = (const float4*)(x + (r0 + 0) * DIM) + t * 2;
  const float4* xB = (const float4*)(x + (r0 + 1) * DIM) + t * 2;
  const float4* xC = (const float4*)(x + (r0 + 2) * DIM) + t * 2;
  const float4* xD = (const float4*)(x + (r0 + 3) * DIM) + t * 2;
  const float4 A0 = xA[0], A1 = xA[1], B0 = xB[0], B1 = xB[1];
  const float4 C0 = xC[0], C1 = xC[1], D0 = xD[0], D1 = xD[1];
  const float va[8] = {A0.x, A0.y, A0.z, A0.w, A1.x, A1.y, A1.z, A1.w};
  const float vb[8] = {B0.x, B0.y, B0.z, B0.w, B1.x, B1.y, B1.z, B1.w};
  const float vc[8] = {C0.x, C0.y, C0.z, C0.w, C1.x, C1.y, C1.z, C1.w};
  const float vd[8] = {D0.x, D0.y, D0.z, D0.w, D1.x, D1.y, D1.z, D1.w};
  float4 ss = make_float4(0.f, 0.f, 0.f, 0.f);
#pragma unroll
  for (int e = 0; e < 8; ++e) {
    ss.x += va[e] * va[e]; ss.y += vb[e] * vb[e];
    ss.z += vc[e] * vc[e]; ss.w += vd[e] * vd[e];
  }
  const float4 nsq = block_reduce_sum4(ss, red);  // barriers also cover gmat
  const float nA = sqrtf(nsq.x), nB = sqrtf(nsq.y);
  const float nC = sqrtf(nsq.z), nD = sqrtf(nsq.w);
  const bool okA = nA > 1e-10f, okB = nB > 1e-10f;
  const bool okC = nC > 1e-10f, okD = nD > 1e-10f;
  const float iA = okA ? 1.0f / nA : 0.f, iB = okB ? 1.0f / nB : 0.f;
  const float iC = okC ? 1.0f / nC : 0.f, iD = okD ? 1.0f / nD : 0.f;

  // encode: identity layout under swz (logical z at position swz(z)) (R7)
#pragma unroll
  for (int e = 0; e < 8; ++e) {
    const int idx = swz(t * 8 + e);
    stX[idx] = make_float4(okA ? va[e] * iA : 0.015625f,
                           okB ? vb[e] * iB : 0.015625f, 0.f, 0.f);
    stY[idx] = make_float4(okC ? vc[e] * iC : 0.015625f,
                           okD ? vd[e] * iD : 0.015625f, 0.f, 0.f);
  }

  // in-place partitions (fixed layout, rotating patterns), all swizzled (R7):
  int p0[8], p1[8], p2[8], p3[8], gd[8];
#pragma unroll
  for (int j = 0; j < 8; ++j) {
    p0[j] = swz(t | (j << 9));
    p1[j] = swz(lane | (j << 6) | (wave << 9));
    p2[j] = swz(a | (j << 3) | (b << 6) | (wave << 9));
    p3[j] = swz(j | (a << 3) | (b << 6) | (wave << 9));
    gd[j] = swz(sfun(t | (j << 9)));
  }
  __syncthreads();

  v2 xr[8], xi[8], yr[8], yi[8];
#pragma unroll
  for (int L = 0; L < NLAYER; ++L) {
    const float2* GL = &gmat[L * NQ * 4];

    // RT0: bits 9-11 (qubits 2,1,0). L>=1: read fuses prev layer's CNOT perm.
    if (L == 0) {
      LOAD8(stX, xr, xi, p0)
      LOAD8(stY, yr, yi, p0)
      gates3<0>(xr, xi, GL);
      STORE8(stX, xr, xi, p0)
      gates3<0>(yr, yi, GL);
      STORE8(stY, yr, yi, p0)
    } else {
      LOAD8(stX, xr, xi, gd)
      LOAD8(stY, yr, yi, gd)
      gates3<0>(xr, xi, GL);
      gates3<0>(yr, yi, GL);
      __syncthreads();  // all gather reads complete before in-place writes
      STORE8(stX, xr, xi, p0)
      STORE8(stY, yr, yi, p0)
    }
    __syncthreads();

    // RT1: bits 6-8 (qubits 5,4,3) — in-place, dual interleaved
    LOAD8(stX, xr, xi, p1)
    LOAD8(stY, yr, yi, p1)
    gates3<1>(xr, xi, GL);
    STORE8(stX, xr, xi, p1)
    gates3<1>(yr, yi, GL);
    STORE8(stY, yr, yi, p1)
    __syncthreads();

    // RT2: bits 3-5 (qubits 8,7,6)
    LOAD8(stX, xr, xi, p2)
    LOAD8(stY, yr, yi, p2)
    gates3<2>(xr, xi, GL);
    STORE8(stX, xr, xi, p2)
    gates3<2>(yr, yi, GL);
    STORE8(stY, yr, yi, p2)
    __syncthreads();

    // RT3: bits 0-2 (qubits 11,10,9)
    LOAD8(stX, xr, xi, p3)
    LOAD8(stY, yr, yi, p3)
    gates3<3>(xr, xi, GL);
    STORE8(stX, xr, xi, p3)
    gates3<3>(yr, yi, GL);
    STORE8(stY, yr, yi, p3)
    __syncthreads();
  }

  // --- output: final perm fused into gather; probs + renormalize, 4 rows ---
  float qa[8], qb[8], qc[8], qd[8];
  float4 ps = make_float4(0.f, 0.f, 0.f, 0.f);
#pragma unroll
  for (int k = 0; k < 8; ++k) {
    const float4 vX = stX[gd[k]];
    const float4 vY = stY[gd[k]];
    qa[k] = vX.x * vX.x + vX.z * vX.z;
    qb[k] = vX.y * vX.y + vX.w * vX.w;
    qc[k] = vY.x * vY.x + vY.z * vY.z;
    qd[k] = vY.y * vY.y + vY.w * vY.w;
    ps.x += qa[k]; ps.y += qb[k]; ps.z += qc[k]; ps.w += qd[k];
  }
  const float4 tot = block_reduce_sum4(ps, red);
  const bool kA = tot.x > 1e-10f, kB = tot.y > 1e-10f;
  const bool kC = tot.z > 1e-10f, kD = tot.w > 1e-10f;
  const float tA = kA ? 1.0f / tot.x : 0.f, tB = kB ? 1.0f / tot.y : 0.f;
  const float tC = kC ? 1.0f / tot.z : 0.f, tD = kD ? 1.0f / tot.w : 0.f;
  float* oA = out + (r0 + 0) * DIM;
  float* oB = out + (r0 + 1) * DIM;
  float* oC = out + (r0 + 2) * DIM;
  float* oD = out + (r0 + 3) * DIM;
#pragma unroll
  for (int k = 0; k < 8; ++k) {
    oA[t + k * NT] = kA ? qa[k] * tA : (1.0f / DIM);
    oB[t + k * NT] = kB ? qb[k] * tB : (1.0f / DIM);
    oC[t + k * NT] = kC ? qc[k] * tC : (1.0f / DIM);
    oD[t + k * NT] = kD ? qd[k] * tD : (1.0f / DIM);
  }
}

extern "C" void kernel_launch(void* const* d_in, const int* in_sizes, int n_in,
                              void* d_out, int out_size, void* d_ws, size_t ws_size,
                              hipStream_t stream) {
  const float* x = (const float*)d_in[0];
  const float* w = (const float*)d_in[1];
  float* out = (float*)d_out;
  const int B = in_sizes[0] / DIM;
  const size_t smem = 2 * DIM * sizeof(float4) + NLAYER * NQ * 4 * sizeof(float2)
                    + (NT / 64) * sizeof(float4);
  qsim_kernel<<<B / 4, NT, smem, stream>>>(x, w, out);
}